// Round 2
// baseline (353.566 us; speedup 1.0000x reference)
//
#include <hip/hip_runtime.h>

// out[i] = (x[i] < tau_i) ? 0 : 1,  tau_i = n_inp*0.6 - count(W[i,:] < 0)
// Memory-bound: read 256 MiB of W once. One 256-thread block per row,
// float4 loads (16 B/lane), wave64 shuffle reduce + 4-slot LDS reduce.

__global__ __launch_bounds__(256) void ltu_rowcount_kernel(
    const float* __restrict__ x,
    const float* __restrict__ W,
    float* __restrict__ out,
    int n_inp) {
  const int row = blockIdx.x;
  const int tid = threadIdx.x;

  const float4* __restrict__ Wrow =
      reinterpret_cast<const float4*>(W + (size_t)row * (size_t)n_inp);
  const int nvec = n_inp >> 2;  // float4's per row (2048 at n_inp=8192)

  int cnt = 0;
  if ((nvec & 255) == 0) {
    // Exact multiple of block size: fixed trip count, full unroll -> deep ILP.
    const int iters = nvec >> 8;  // nvec / 256
#pragma unroll 8
    for (int j = 0; j < iters; ++j) {
      float4 v = Wrow[tid + (j << 8)];
      cnt += (v.x < 0.0f) ? 1 : 0;
      cnt += (v.y < 0.0f) ? 1 : 0;
      cnt += (v.z < 0.0f) ? 1 : 0;
      cnt += (v.w < 0.0f) ? 1 : 0;
    }
  } else {
#pragma unroll 4
    for (int i = tid; i < nvec; i += 256) {
      float4 v = Wrow[i];
      cnt += (v.x < 0.0f) ? 1 : 0;
      cnt += (v.y < 0.0f) ? 1 : 0;
      cnt += (v.z < 0.0f) ? 1 : 0;
      cnt += (v.w < 0.0f) ? 1 : 0;
    }
  }

  // wave64 reduction
#pragma unroll
  for (int off = 32; off > 0; off >>= 1) cnt += __shfl_down(cnt, off, 64);

  __shared__ int scnt[4];
  const int lane = tid & 63;
  const int wid = tid >> 6;
  if (lane == 0) scnt[wid] = cnt;
  __syncthreads();

  if (tid == 0) {
    const int total = scnt[0] + scnt[1] + scnt[2] + scnt[3];
    const float tau = (float)n_inp * 0.6f - (float)total;
    out[row] = (x[row] < tau) ? 0.0f : 1.0f;
  }
}

extern "C" void kernel_launch(void* const* d_in, const int* in_sizes, int n_in,
                              void* d_out, int out_size, void* d_ws, size_t ws_size,
                              hipStream_t stream) {
  const float* x = (const float*)d_in[0];   // [n_tl1] fp32
  const float* W = (const float*)d_in[1];   // [n_tl1, n_inp] fp32
  float* out = (float*)d_out;               // [n_tl1] fp32

  const int n_tl1 = in_sizes[0];
  const int n_inp = in_sizes[1] / n_tl1;

  ltu_rowcount_kernel<<<n_tl1, 256, 0, stream>>>(x, W, out, n_inp);
}

// Round 3
// 352.127 us; speedup vs baseline: 1.0041x; 1.0041x over previous
//
#include <hip/hip_runtime.h>

// out[i] = (x[i] < tau_i) ? 0 : 1,  tau_i = n_inp*0.6 - count(W[i,:] < 0)
// Memory-bound: read 256 MiB of W once (~43 us floor at 6.3 TB/s).
// Wave-per-row: 2048 blocks x 256 thr (G11 grid cap), each wave owns a row.
// 32 independent float4 loads per lane, in-wave shuffle reduce.
// No __syncthreads, no LDS.

__global__ __launch_bounds__(256) void ltu_rowcount_kernel(
    const float* __restrict__ x,
    const float* __restrict__ W,
    float* __restrict__ out,
    int n_inp, int n_rows) {
  const int lane = threadIdx.x & 63;
  const int nvec = n_inp >> 2;  // float4's per row (2048 at n_inp=8192)
  const int waves_in_grid = (gridDim.x * blockDim.x) >> 6;
  const int my_wave = (blockIdx.x * blockDim.x + threadIdx.x) >> 6;

  for (int row = my_wave; row < n_rows; row += waves_in_grid) {
    const float4* __restrict__ Wrow =
        reinterpret_cast<const float4*>(W + (size_t)row * (size_t)n_inp);
    int cnt = 0;
#pragma unroll 8
    for (int i = lane; i < nvec; i += 64) {
      float4 v = Wrow[i];
      cnt += (v.x < 0.0f) ? 1 : 0;
      cnt += (v.y < 0.0f) ? 1 : 0;
      cnt += (v.z < 0.0f) ? 1 : 0;
      cnt += (v.w < 0.0f) ? 1 : 0;
    }

    // wave64 shuffle reduction
#pragma unroll
    for (int off = 32; off > 0; off >>= 1) cnt += __shfl_down(cnt, off, 64);

    if (lane == 0) {
      const float tau = (float)n_inp * 0.6f - (float)cnt;
      out[row] = (x[row] < tau) ? 0.0f : 1.0f;
    }
  }
}

extern "C" void kernel_launch(void* const* d_in, const int* in_sizes, int n_in,
                              void* d_out, int out_size, void* d_ws, size_t ws_size,
                              hipStream_t stream) {
  const float* x = (const float*)d_in[0];   // [n_tl1] fp32
  const float* W = (const float*)d_in[1];   // [n_tl1, n_inp] fp32
  float* out = (float*)d_out;               // [n_tl1] fp32

  const int n_tl1 = in_sizes[0];
  const int n_inp = in_sizes[1] / n_tl1;

  // G11: ~2048 blocks, grid-stride. 2048 blocks x 4 waves = 8192 waves,
  // exactly one row per wave at the reference shape.
  int blocks = (n_tl1 + 3) / 4;
  if (blocks > 2048) blocks = 2048;

  ltu_rowcount_kernel<<<blocks, 256, 0, stream>>>(x, W, out, n_inp, n_tl1);
}